// Round 3
// baseline (613.904 us; speedup 1.0000x reference)
//
#include <hip/hip_runtime.h>
#include <stdint.h>

// AWQ 4-bit fused dequant GEMM: out[M,N] = x[M,K] @ W[N,K]^T + bias
// fp16 MFMA 16x16x32, BM=128 BN=128 BK=64, 4 waves (2x2, 64x64 each),
// acc[4][4]=64 AGPR for 3 waves/SIMD occupancy, XOR-swizzled LDS,
// 2-phase reg-prefetch, fp16 magic-number dequant, XCD chunk swizzle.
// No prepass, no workspace (avoids the R2 cross-XCD dirty-line write blowup).

#define BM 128
#define BN 128
#define BK 64

typedef _Float16 f16x2 __attribute__((ext_vector_type(2)));
typedef _Float16 f16x8 __attribute__((ext_vector_type(8)));
typedef float f32x4 __attribute__((ext_vector_type(4)));

__global__ __launch_bounds__(256, 3) void awq_gemm_kernel(
    const float* __restrict__ x,
    const int*   __restrict__ qw,
    const int*   __restrict__ qz,
    const float* __restrict__ sc,
    const float* __restrict__ bias,
    float*       __restrict__ out,
    int M, int N, int K)
{
    __shared__ __align__(16) unsigned short As[BM * BK];  // 16 KB
    __shared__ __align__(16) unsigned short Bs[BN * BK];  // 16 KB

    const int tid  = threadIdx.x;
    const int lane = tid & 63;
    const int wave = tid >> 6;           // 0..3
    const int wr   = wave >> 1;          // 64-row half
    const int wc   = wave & 1;           // 64-col half
    const int lrow = lane & 15;
    const int lko  = (lane >> 4) << 3;   // k chunk 0,8,16,24

    // XCD-aware chunked swizzle: 2048 blocks, %8==0 -> bijective
    const int cpx = gridDim.x >> 3;
    const int bid = (blockIdx.x & 7) * cpx + (blockIdx.x >> 3);
    const int ntn = N / BN;              // 32
    const int m0 = (bid / ntn) * BM;
    const int n0 = (bid % ntn) * BN;

    const int ngrp = K >> 7;             // 32
    const int nzw  = ngrp >> 3;          // 4
    const int kw   = K >> 3;             // int32 per qweight row
    const int NT   = K / BK;             // 64

    // staging map: 2 threads per row, each owns a 32-k half
    const int r_s = tid >> 1;            // 0..127
    const int kh  = tid & 1;             // 0/1 -> k offset 0/32
    const int sws = (r_s & 7) << 3;      // LDS XOR swizzle (elements)

    f32x4 acc[4][4];
    #pragma unroll
    for (int m = 0; m < 4; ++m)
        #pragma unroll
        for (int n = 0; n < 4; ++n)
            #pragma unroll
            for (int e = 0; e < 4; ++e) acc[m][n][e] = 0.f;

    // prefetch registers
    float4  a32[8];     // 32 floats of x
    uint32_t bq[4];     // 4 qweight words (32 nibbles)
    float    bs;
    uint32_t bz;

    auto LOADA = [&](int kt) {
        const float* p = x + (size_t)(m0 + r_s) * K + kt + kh * 32;
        #pragma unroll
        for (int i = 0; i < 8; ++i)
            a32[i] = *reinterpret_cast<const float4*>(p + 4 * i);
    };
    auto LOADB = [&](int kt) {
        const int4* p = reinterpret_cast<const int4*>(
            qw + (size_t)(n0 + r_s) * kw + (kt >> 3) + kh * 4);
        *reinterpret_cast<int4*>(&bq[0]) = p[0];
        int grp = kt >> 7;
        bs = sc[(size_t)(n0 + r_s) * ngrp + grp];
        bz = ((uint32_t)qz[(size_t)(n0 + r_s) * nzw + (grp >> 3)] >> ((grp & 7) << 2)) & 0xF;
    };
    auto WRITEA = [&]() {
        #pragma unroll
        for (int c = 0; c < 4; ++c) {
            // chunk of 8 floats -> pair-permuted fp16 words
            uint4 o;
            o.x = __builtin_bit_cast(uint32_t, __builtin_amdgcn_cvt_pkrtz(a32[2*c].x, a32[2*c+1].x));
            o.y = __builtin_bit_cast(uint32_t, __builtin_amdgcn_cvt_pkrtz(a32[2*c].y, a32[2*c+1].y));
            o.z = __builtin_bit_cast(uint32_t, __builtin_amdgcn_cvt_pkrtz(a32[2*c].z, a32[2*c+1].z));
            o.w = __builtin_bit_cast(uint32_t, __builtin_amdgcn_cvt_pkrtz(a32[2*c].w, a32[2*c+1].w));
            int kcol = kh * 32 + 8 * c;
            *reinterpret_cast<uint4*>(&As[r_s * BK + (kcol ^ sws)]) = o;
        }
    };
    auto WRITEB = [&]() {
        _Float16 hs = (_Float16)bs;
        _Float16 hz = (_Float16)(1024.0f + (float)bz);   // <=1039: exact in fp16
        f16x2 s2 = {hs, hs};
        f16x2 z2 = {hz, hz};
        const uint32_t MK = 0x000F000Fu, MG = 0x64006400u;
        #pragma unroll
        for (int j = 0; j < 4; ++j) {
            uint32_t u = bq[j];
            uint32_t t0 = (u & MK) | MG;
            uint32_t t1 = ((u >> 4) & MK) | MG;
            uint32_t t2 = ((u >> 8) & MK) | MG;
            uint32_t t3 = ((u >> 12) & MK) | MG;
            f16x2 w0 = (__builtin_bit_cast(f16x2, t0) - z2) * s2;
            f16x2 w1 = (__builtin_bit_cast(f16x2, t1) - z2) * s2;
            f16x2 w2 = (__builtin_bit_cast(f16x2, t2) - z2) * s2;
            f16x2 w3 = (__builtin_bit_cast(f16x2, t3) - z2) * s2;
            uint4 o;
            o.x = __builtin_bit_cast(uint32_t, w0);
            o.y = __builtin_bit_cast(uint32_t, w1);
            o.z = __builtin_bit_cast(uint32_t, w2);
            o.w = __builtin_bit_cast(uint32_t, w3);
            int kcol = kh * 32 + 8 * j;
            *reinterpret_cast<uint4*>(&Bs[r_s * BK + (kcol ^ sws)]) = o;
        }
    };

    LOADA(0); LOADB(0);

    for (int t = 0; t < NT; ++t) {
        WRITEA();
        WRITEB();
        __syncthreads();
        if (t + 1 < NT) { LOADA((t + 1) * BK); LOADB((t + 1) * BK); }
        #pragma unroll
        for (int kk = 0; kk < 2; ++kk) {
            f16x8 af[4], bf[4];
            #pragma unroll
            for (int m = 0; m < 4; ++m) {
                int arow = wr * 64 + m * 16 + lrow;
                int idx = arow * BK + ((kk * 32 + lko) ^ ((arow & 7) << 3));
                af[m] = __builtin_bit_cast(f16x8,
                        *reinterpret_cast<const uint4*>(&As[idx]));
            }
            #pragma unroll
            for (int n = 0; n < 4; ++n) {
                int brow = wc * 64 + n * 16 + lrow;
                int idx = brow * BK + ((kk * 32 + lko) ^ ((brow & 7) << 3));
                bf[n] = __builtin_bit_cast(f16x8,
                        *reinterpret_cast<const uint4*>(&Bs[idx]));
            }
            #pragma unroll
            for (int m = 0; m < 4; ++m)
                #pragma unroll
                for (int n = 0; n < 4; ++n)
                    acc[m][n] = __builtin_amdgcn_mfma_f32_16x16x32_f16(
                        af[m], bf[n], acc[m][n], 0, 0, 0);
        }
        __syncthreads();
    }

    // epilogue: C frag mapping col=lane&15, row=(lane>>4)*4+e
    const int r4 = (lane >> 4) << 2;
    #pragma unroll
    for (int n = 0; n < 4; ++n) {
        int col = n0 + wc * 64 + n * 16 + lrow;
        float bv = bias[col];
        #pragma unroll
        for (int m = 0; m < 4; ++m) {
            size_t rbase = (size_t)(m0 + wr * 64 + m * 16 + r4) * N + col;
            #pragma unroll
            for (int e = 0; e < 4; ++e)
                __builtin_nontemporal_store(acc[m][n][e] + bv, &out[rbase + (size_t)e * N]);
        }
    }
}

extern "C" void kernel_launch(void* const* d_in, const int* in_sizes, int n_in,
                              void* d_out, int out_size, void* d_ws, size_t ws_size,
                              hipStream_t stream) {
    const float* x   = (const float*)d_in[0];
    const int*   qwp = (const int*)d_in[1];
    const int*   qzp = (const int*)d_in[2];
    const float* scp = (const float*)d_in[3];
    const float* bp  = (const float*)d_in[4];
    float* outp = (float*)d_out;

    const int N = in_sizes[4];                 // 4096 (O)
    const int K = (in_sizes[1] / N) * 8;       // 4096 (I)
    const int M = in_sizes[0] / K;             // 8192 (B)

    dim3 grid((M / BM) * (N / BN));            // 64*32 = 2048
    dim3 block(256);
    awq_gemm_kernel<<<grid, block, 0, stream>>>(x, qwp, qzp, scp, bp, outp, M, N, K);
}

// Round 4
// 468.917 us; speedup vs baseline: 1.3092x; 1.3092x over previous
//
#include <hip/hip_runtime.h>
#include <stdint.h>

// AWQ 4-bit fused dequant GEMM: out[M,N] = x[M,K] @ W[N,K]^T + bias
// fp16 MFMA 16x16x32. BM=BN=256, BK=64, 512 threads (8 waves, 2x4 of 128x64).
// Double-buffered dynamic LDS (128 KB), ONE barrier per K-tile, reg-prefetch
// one tile ahead, fp16 magic-number dequant, XOR-swizzled LDS, XCD chunk swizzle.
// Fallback template BK=32 (64 KB LDS) if large dynamic LDS is unavailable.

#define BM 256
#define BN 256

typedef _Float16 f16x2 __attribute__((ext_vector_type(2)));
typedef _Float16 f16x8 __attribute__((ext_vector_type(8)));
typedef float f32x4 __attribute__((ext_vector_type(4)));

template <int BK>
__global__ __launch_bounds__(512, 2) void awq_gemm_kernel(
    const float* __restrict__ x,
    const int*   __restrict__ qw,
    const int*   __restrict__ qz,
    const float* __restrict__ sc,
    const float* __restrict__ bias,
    float*       __restrict__ out,
    int M, int N, int K)
{
    extern __shared__ __align__(16) unsigned short lds[];
    unsigned short* As = lds;                    // [2][BM*BK]
    unsigned short* Bs = lds + 2 * BM * BK;      // [2][BN*BK]

    const int tid  = threadIdx.x;
    const int lane = tid & 63;
    const int wave = tid >> 6;            // 0..7
    const int wr   = wave >> 2;           // 0..1 -> 128-row half
    const int wc   = wave & 3;            // 0..3 -> 64-col quarter
    const int lrow = lane & 15;
    const int lko  = (lane >> 4) << 3;    // k chunk 0,8,16,24

    // XCD-aware chunked swizzle (512 blocks, %8==0 -> bijective)
    const int cpx = gridDim.x >> 3;
    const int bid = (blockIdx.x & 7) * cpx + (blockIdx.x >> 3);
    const int ntn = N / BN;               // 16
    const int m0 = (bid / ntn) * BM;
    const int n0 = (bid % ntn) * BN;

    const int ngrp = K >> 7;              // 32
    const int nzw  = ngrp >> 3;           // 4
    const int kw   = K >> 3;              // int32 per qweight row
    const int NT   = K / BK;

    // staging map: 2 threads per row, each owns a (BK/2)-k half
    const int r_s = tid >> 1;             // 0..255
    const int kh  = tid & 1;
    const int sws = (r_s & (BK / 8 - 1)) << 3;   // LDS XOR swizzle (elements)

    f32x4 acc[8][4];
    #pragma unroll
    for (int m = 0; m < 8; ++m)
        #pragma unroll
        for (int n = 0; n < 4; ++n)
            #pragma unroll
            for (int e = 0; e < 4; ++e) acc[m][n][e] = 0.f;

    // prefetch registers
    float4   a32[BK / 8];     // BK/2 floats of x
    uint32_t bq[BK / 16];     // qweight words (8 nibbles each)
    float    bs_;
    uint32_t bz_;

    auto LOADA = [&](int kt) {
        const float* p = x + (size_t)(m0 + r_s) * K + kt + kh * (BK / 2);
        #pragma unroll
        for (int i = 0; i < BK / 8; ++i)
            a32[i] = *reinterpret_cast<const float4*>(p + 4 * i);
    };
    auto LOADB = [&](int kt) {
        const int* p = qw + (size_t)(n0 + r_s) * kw + (kt >> 3) + kh * (BK / 16);
        if constexpr (BK == 64) {
            int4 v = *reinterpret_cast<const int4*>(p);
            bq[0] = v.x; bq[1] = v.y; bq[2] = v.z; bq[3] = v.w;
        } else {
            int2 v = *reinterpret_cast<const int2*>(p);
            bq[0] = v.x; bq[1] = v.y;
        }
        int grp = kt >> 7;
        bs_ = sc[(size_t)(n0 + r_s) * ngrp + grp];
        bz_ = ((uint32_t)qz[(size_t)(n0 + r_s) * nzw + (grp >> 3)] >> ((grp & 7) << 2)) & 0xF;
    };
    auto WRITEA = [&](int buf) {
        unsigned short* dst = As + buf * (BM * BK);
        #pragma unroll
        for (int c = 0; c < BK / 16; ++c) {
            uint4 o;
            o.x = __builtin_bit_cast(uint32_t, __builtin_amdgcn_cvt_pkrtz(a32[2*c].x, a32[2*c+1].x));
            o.y = __builtin_bit_cast(uint32_t, __builtin_amdgcn_cvt_pkrtz(a32[2*c].y, a32[2*c+1].y));
            o.z = __builtin_bit_cast(uint32_t, __builtin_amdgcn_cvt_pkrtz(a32[2*c].z, a32[2*c+1].z));
            o.w = __builtin_bit_cast(uint32_t, __builtin_amdgcn_cvt_pkrtz(a32[2*c].w, a32[2*c+1].w));
            int kcol = kh * (BK / 2) + 8 * c;
            *reinterpret_cast<uint4*>(&dst[r_s * BK + (kcol ^ sws)]) = o;
        }
    };
    auto WRITEB = [&](int buf) {
        unsigned short* dst = Bs + buf * (BN * BK);
        _Float16 hs = (_Float16)bs_;
        _Float16 hz = (_Float16)(1024.0f + (float)bz_);  // <=1039: exact in fp16
        f16x2 s2 = {hs, hs};
        f16x2 z2 = {hz, hz};
        const uint32_t MK = 0x000F000Fu, MG = 0x64006400u;
        #pragma unroll
        for (int j = 0; j < BK / 16; ++j) {
            uint32_t u = bq[j];
            uint32_t t0 = (u & MK) | MG;
            uint32_t t1 = ((u >> 4) & MK) | MG;
            uint32_t t2 = ((u >> 8) & MK) | MG;
            uint32_t t3 = ((u >> 12) & MK) | MG;
            f16x2 w0 = (__builtin_bit_cast(f16x2, t0) - z2) * s2;
            f16x2 w1 = (__builtin_bit_cast(f16x2, t1) - z2) * s2;
            f16x2 w2 = (__builtin_bit_cast(f16x2, t2) - z2) * s2;
            f16x2 w3 = (__builtin_bit_cast(f16x2, t3) - z2) * s2;
            uint4 o;
            o.x = __builtin_bit_cast(uint32_t, w0);
            o.y = __builtin_bit_cast(uint32_t, w1);
            o.z = __builtin_bit_cast(uint32_t, w2);
            o.w = __builtin_bit_cast(uint32_t, w3);
            int kcol = kh * (BK / 2) + 8 * j;
            *reinterpret_cast<uint4*>(&dst[r_s * BK + (kcol ^ sws)]) = o;
        }
    };

    LOADA(0); LOADB(0);

    for (int t = 0; t < NT; ++t) {
        const int buf = t & 1;
        WRITEA(buf);
        WRITEB(buf);
        if (t + 1 < NT) { LOADA((t + 1) * BK); LOADB((t + 1) * BK); }
        __syncthreads();
        const unsigned short* Ab = As + buf * (BM * BK);
        const unsigned short* Bb = Bs + buf * (BN * BK);
        #pragma unroll
        for (int kk = 0; kk < BK / 32; ++kk) {
            f16x8 af[8], bf[4];
            #pragma unroll
            for (int m = 0; m < 8; ++m) {
                int arow = wr * 128 + m * 16 + lrow;
                int idx = arow * BK + ((kk * 32 + lko) ^ ((arow & (BK/8 - 1)) << 3));
                af[m] = __builtin_bit_cast(f16x8,
                        *reinterpret_cast<const uint4*>(&Ab[idx]));
            }
            #pragma unroll
            for (int n = 0; n < 4; ++n) {
                int brow = wc * 64 + n * 16 + lrow;
                int idx = brow * BK + ((kk * 32 + lko) ^ ((brow & (BK/8 - 1)) << 3));
                bf[n] = __builtin_bit_cast(f16x8,
                        *reinterpret_cast<const uint4*>(&Bb[idx]));
            }
            #pragma unroll
            for (int m = 0; m < 8; ++m)
                #pragma unroll
                for (int n = 0; n < 4; ++n)
                    acc[m][n] = __builtin_amdgcn_mfma_f32_16x16x32_f16(
                        af[m], bf[n], acc[m][n], 0, 0, 0);
        }
        // no trailing barrier: next iteration writes the OTHER buffer; the
        // barrier above (iteration t+1) orders buf reuse at t+2 vs reads at t.
    }

    // epilogue: C frag mapping col=lane&15, row=(lane>>4)*4+e
    const int r4 = (lane >> 4) << 2;
    #pragma unroll
    for (int n = 0; n < 4; ++n) {
        int col = n0 + wc * 64 + n * 16 + lrow;
        float bv = bias[col];
        #pragma unroll
        for (int m = 0; m < 8; ++m) {
            size_t rbase = (size_t)(m0 + wr * 128 + m * 16 + r4) * N + col;
            #pragma unroll
            for (int e = 0; e < 4; ++e)
                __builtin_nontemporal_store(acc[m][n][e] + bv, &out[rbase + (size_t)e * N]);
        }
    }
}

extern "C" void kernel_launch(void* const* d_in, const int* in_sizes, int n_in,
                              void* d_out, int out_size, void* d_ws, size_t ws_size,
                              hipStream_t stream) {
    const float* x   = (const float*)d_in[0];
    const int*   qwp = (const int*)d_in[1];
    const int*   qzp = (const int*)d_in[2];
    const float* scp = (const float*)d_in[3];
    const float* bp  = (const float*)d_in[4];
    float* outp = (float*)d_out;

    const int N = in_sizes[4];                 // 4096 (O)
    const int K = (in_sizes[1] / N) * 8;       // 4096 (I)
    const int M = in_sizes[0] / K;             // 8192 (B)

    dim3 grid((M / BM) * (N / BN));            // 32*16 = 512
    dim3 block(512);

    const int lds64 = 2 * (BM + BN) * 64 * 2;  // 131072 B
    hipError_t err = hipFuncSetAttribute(
        reinterpret_cast<const void*>(&awq_gemm_kernel<64>),
        hipFuncAttributeMaxDynamicSharedMemorySize, lds64);
    if (err == hipSuccess) {
        awq_gemm_kernel<64><<<grid, block, lds64, stream>>>(
            x, qwp, qzp, scp, bp, outp, M, N, K);
    } else {
        const int lds32 = 2 * (BM + BN) * 32 * 2;  // 65536 B
        (void)hipFuncSetAttribute(
            reinterpret_cast<const void*>(&awq_gemm_kernel<32>),
            hipFuncAttributeMaxDynamicSharedMemorySize, lds32);
        awq_gemm_kernel<32><<<grid, block, lds32, stream>>>(
            x, qwp, qzp, scp, bp, outp, M, N, K);
    }
}